// Round 3
// baseline (197.354 us; speedup 1.0000x reference)
//
#include <hip/hip_runtime.h>
#include <math.h>

// Problem constants
#define BB 2
#define DM 96
#define DI 192
#define DST 16
#define DRK 6
#define LL 4096
#define NCH 128     // number of scan chunks
#define CT 32       // chunk length (NCH*CT == LL)

// spatial (i,j) -> scan index, closed form of diagonal_order's argsort
__device__ __forceinline__ int inv_ord(int i, int j) {
    if (i == j) return i;
    if (j > i)  return 64 + i * 63 - (i * (i - 1)) / 2 + (j - i - 1);
    return 2080 + (i * (i - 1)) / 2 + j;
}

__device__ __forceinline__ float silu_f(float v) {
    return v / (1.f + expf(-v));
}

// ---------------- K1: xz = x @ w_in^T ; split into xi and silu(z) ----------
// M = B*H*W = 8192, N = 384, K = 96. Tile 64x64, block 256, whole K in LDS.
__global__ __launch_bounds__(256) void k_gemm_in(const float* __restrict__ x,
                                                 const float* __restrict__ w_in,
                                                 float* __restrict__ xi,
                                                 float* __restrict__ zs) {
    __shared__ float aT[96][68];   // [k][m], padded for b128-aligned reads
    __shared__ float bT[96][68];   // [k][n]
    const int tid = threadIdx.x;
    const int bm = blockIdx.x, bn = blockIdx.y;

    for (int f = tid; f < 64 * 24; f += 256) {
        int mm = f / 24, k4 = f % 24;
        float4 v = *(const float4*)(x + (size_t)(bm * 64 + mm) * 96 + k4 * 4);
        aT[k4 * 4 + 0][mm] = v.x; aT[k4 * 4 + 1][mm] = v.y;
        aT[k4 * 4 + 2][mm] = v.z; aT[k4 * 4 + 3][mm] = v.w;
    }
    for (int f = tid; f < 64 * 24; f += 256) {
        int nn = f / 24, k4 = f % 24;
        float4 v = *(const float4*)(w_in + (size_t)(bn * 64 + nn) * 96 + k4 * 4);
        bT[k4 * 4 + 0][nn] = v.x; bT[k4 * 4 + 1][nn] = v.y;
        bT[k4 * 4 + 2][nn] = v.z; bT[k4 * 4 + 3][nn] = v.w;
    }
    __syncthreads();

    const int tn = tid & 15, tm = tid >> 4;
    float acc[4][4] = {};
#pragma unroll 4
    for (int k = 0; k < 96; ++k) {
        float4 av = *(const float4*)&aT[k][tm * 4];
        float4 bv = *(const float4*)&bT[k][tn * 4];
        acc[0][0] += av.x * bv.x; acc[0][1] += av.x * bv.y; acc[0][2] += av.x * bv.z; acc[0][3] += av.x * bv.w;
        acc[1][0] += av.y * bv.x; acc[1][1] += av.y * bv.y; acc[1][2] += av.y * bv.z; acc[1][3] += av.y * bv.w;
        acc[2][0] += av.z * bv.x; acc[2][1] += av.z * bv.y; acc[2][2] += av.z * bv.z; acc[2][3] += av.z * bv.w;
        acc[3][0] += av.w * bv.x; acc[3][1] += av.w * bv.y; acc[3][2] += av.w * bv.z; acc[3][3] += av.w * bv.w;
    }

#pragma unroll
    for (int i = 0; i < 4; ++i) {
#pragma unroll
        for (int j = 0; j < 4; ++j) {
            int m = bm * 64 + tm * 4 + i;
            int n = bn * 64 + tn * 4 + j;
            float v = acc[i][j];
            if (n < DI) xi[(size_t)m * DI + n] = v;
            else        zs[(size_t)m * DI + (n - DI)] = silu_f(v);
        }
    }
}

// ---------------- K2: depthwise 3x3 conv + bias + silu, write in scan order
__global__ __launch_bounds__(256) void k_conv(const float* __restrict__ xi,
                                              const float* __restrict__ cw,
                                              const float* __restrict__ cb,
                                              float* __restrict__ xs0) {
    int t = blockIdx.x * 256 + threadIdx.x;   // < 2*4096*48
    int c4 = t % 48;
    int p = t / 48;
    int b = p >> 12;
    int hw = p & 4095;
    int i = hw >> 6, j = hw & 63;
    int c = c4 * 4;
    float a0 = cb[c], a1 = cb[c + 1], a2 = cb[c + 2], a3 = cb[c + 3];
#pragma unroll
    for (int kh = -1; kh <= 1; ++kh) {
        int i2 = i + kh;
        if (i2 < 0 || i2 > 63) continue;
#pragma unroll
        for (int kw = -1; kw <= 1; ++kw) {
            int j2 = j + kw;
            if (j2 < 0 || j2 > 63) continue;
            float4 v = *(const float4*)(xi + ((size_t)(b << 12) + (i2 << 6) + j2) * DI + c);
            int wi = (kh + 1) * 3 + (kw + 1);
            a0 += v.x * cw[(c + 0) * 9 + wi];
            a1 += v.y * cw[(c + 1) * 9 + wi];
            a2 += v.z * cw[(c + 2) * 9 + wi];
            a3 += v.w * cw[(c + 3) * 9 + wi];
        }
    }
    a0 = silu_f(a0); a1 = silu_f(a1); a2 = silu_f(a2); a3 = silu_f(a3);
    int m = inv_ord(i, j);
    *(float4*)(xs0 + ((size_t)(b << 12) + m) * DI + c) = make_float4(a0, a1, a2, a3);
}

// ---------------- K3: x-proj (38x192) + dt-proj (192x6) + softplus ---------
// GEMM-structured: 64 positions per block, X staged in LDS [kk4][pos],
// weights via wave-uniform scalar loads; no shuffles.
__global__ __launch_bounds__(256) void k_proj2(const float* __restrict__ xs0,
                                               const float* __restrict__ xpw,
                                               const float* __restrict__ dtw,
                                               const float* __restrict__ dtb,
                                               float* __restrict__ delta,
                                               float* __restrict__ Bsv,
                                               float* __restrict__ Csv) {
    __shared__ float4 xls[48 * 64];   // [kk4][pos], 48 KB
    __shared__ float  tls[38 * 64];   // [c][pos],   9.5 KB
    const int tid = threadIdx.x;
    const int bk = blockIdx.x >> 6;   // 0..3  (b,k)
    const int pc = blockIdx.x & 63;   // 64-position chunk within bk
    const int b = bk >> 1, k = bk & 1;

    // stage 64 x-rows (already in scan order for this k) into LDS
    for (int f = tid; f < 64 * 48; f += 256) {
        int i = f / 48, kk4 = f % 48;
        int l = pc * 64 + i;
        int msrc = k ? (4095 - l) : l;
        xls[kk4 * 64 + i] = *(const float4*)(xs0 + ((size_t)(b << 12) + msrc) * DI + kk4 * 4);
    }
    __syncthreads();

    // phase 1: t[c][pos] = dot(xpw[k][c][:], x[pos][:]) — lane = pos,
    // 4 channels per iteration, weights wave-uniform -> SGPR operands
    {
        int wu = __builtin_amdgcn_readfirstlane(tid >> 6);  // wave id 0..3
        int lane = tid & 63;
        int cstart = (wu < 2) ? wu * 10 : 20 + (wu - 2) * 9;
        int cend = cstart + ((wu < 2) ? 10 : 9);
        const float* wb = xpw + (size_t)k * 38 * DI;
        for (int cc = cstart; cc < cend; cc += 4) {
            int c0 = cc;
            int c1 = (cc + 1 < cend) ? cc + 1 : cc;
            int c2 = (cc + 2 < cend) ? cc + 2 : cc;
            int c3 = (cc + 3 < cend) ? cc + 3 : cc;
            float a0 = 0.f, a1 = 0.f, a2 = 0.f, a3 = 0.f;
#pragma unroll 4
            for (int q = 0; q < 48; ++q) {
                float4 xv = xls[q * 64 + lane];
                float4 w0 = *(const float4*)(wb + c0 * DI + q * 4);
                float4 w1 = *(const float4*)(wb + c1 * DI + q * 4);
                float4 w2 = *(const float4*)(wb + c2 * DI + q * 4);
                float4 w3 = *(const float4*)(wb + c3 * DI + q * 4);
                a0 += xv.x * w0.x + xv.y * w0.y + xv.z * w0.z + xv.w * w0.w;
                a1 += xv.x * w1.x + xv.y * w1.y + xv.z * w1.z + xv.w * w1.w;
                a2 += xv.x * w2.x + xv.y * w2.y + xv.z * w2.z + xv.w * w2.w;
                a3 += xv.x * w3.x + xv.y * w3.y + xv.z * w3.z + xv.w * w3.w;
            }
            tls[c0 * 64 + lane] = a0;
            if (cc + 1 < cend) tls[(cc + 1) * 64 + lane] = a1;
            if (cc + 2 < cend) tls[(cc + 2) * 64 + lane] = a2;
            if (cc + 3 < cend) tls[(cc + 3) * 64 + lane] = a3;
        }
    }
    __syncthreads();

    // phase 2a (waves 0-2): dt-proj + softplus, d = tid, coalesced stores
    if (tid < DI) {
        int d = tid;
        const float* dwr = dtw + ((size_t)k * DI + d) * 6;
        float w0 = dwr[0], w1 = dwr[1], w2 = dwr[2];
        float w3 = dwr[3], w4 = dwr[4], w5 = dwr[5];
        float bias = dtb[k * DI + d];
        int posg0 = (bk << 12) + pc * 64;
        for (int pos = 0; pos < 64; ++pos) {
            float acc = bias
                + tls[0 * 64 + pos] * w0 + tls[1 * 64 + pos] * w1
                + tls[2 * 64 + pos] * w2 + tls[3 * 64 + pos] * w3
                + tls[4 * 64 + pos] * w4 + tls[5 * 64 + pos] * w5;
            float sp = acc > 20.f ? acc : log1pf(expf(acc));
            delta[(size_t)(posg0 + pos) * DI + d] = sp;
        }
    } else {
        // phase 2b (wave 3): emit B and C, one position per lane
        int pos = tid - DI;
        size_t posg = (size_t)(bk << 12) + pc * 64 + pos;
#pragma unroll
        for (int q2 = 0; q2 < 4; ++q2) {
            float4 bv = make_float4(tls[(6 + q2 * 4 + 0) * 64 + pos],
                                    tls[(6 + q2 * 4 + 1) * 64 + pos],
                                    tls[(6 + q2 * 4 + 2) * 64 + pos],
                                    tls[(6 + q2 * 4 + 3) * 64 + pos]);
            *(float4*)(Bsv + posg * 16 + q2 * 4) = bv;
            float4 cv = make_float4(tls[(22 + q2 * 4 + 0) * 64 + pos],
                                    tls[(22 + q2 * 4 + 1) * 64 + pos],
                                    tls[(22 + q2 * 4 + 2) * 64 + pos],
                                    tls[(22 + q2 * 4 + 3) * 64 + pos]);
            *(float4*)(Csv + posg * 16 + q2 * 4) = cv;
        }
    }
}

// ---------------- K4a: per-chunk scan from h=0, record (prod a, h_end) -----
__global__ __launch_bounds__(256) void k_scan_a(const float* __restrict__ delta,
                                                const float* __restrict__ xs0,
                                                const float* __restrict__ Bsv,
                                                const float* __restrict__ A_logs,
                                                float* __restrict__ aprod,
                                                float* __restrict__ hend) {
    int blk = blockIdx.x;                // 4*3*NCH
    int c = blk & (NCH - 1);
    int rest = blk >> 7;
    int dt = rest % 3;
    int bk = rest / 3;
    int b = bk >> 1, k = bk & 1;
    int tid = threadIdx.x;
    int dd = tid >> 2, ng = tid & 3;
    int d = dt * 64 + dd;

    const size_t abase = ((size_t)k * DI + d) * 16 + ng * 4;
    float Av0 = -expf(A_logs[abase + 0]);
    float Av1 = -expf(A_logs[abase + 1]);
    float Av2 = -expf(A_logs[abase + 2]);
    float Av3 = -expf(A_logs[abase + 3]);

    float h0 = 0, h1 = 0, h2 = 0, h3 = 0;
    float p0 = 1, p1 = 1, p2 = 1, p3 = 1;
    const int posbase = bk << 12;
#pragma unroll 4
    for (int l = 0; l < CT; ++l) {
        int gl = c * CT + l;
        float dl = delta[((size_t)(posbase + gl)) * DI + d];
        int msrc = k ? (4095 - gl) : gl;
        float xv = xs0[((size_t)(b << 12) + msrc) * DI + d];
        float4 bv = *(const float4*)(Bsv + ((size_t)(posbase + gl)) * 16 + ng * 4);
        float dx = dl * xv;
        float a0 = expf(dl * Av0), a1 = expf(dl * Av1);
        float a2 = expf(dl * Av2), a3 = expf(dl * Av3);
        h0 = a0 * h0 + dx * bv.x; h1 = a1 * h1 + dx * bv.y;
        h2 = a2 * h2 + dx * bv.z; h3 = a3 * h3 + dx * bv.w;
        p0 *= a0; p1 *= a1; p2 *= a2; p3 *= a3;
    }
    size_t idx = (((size_t)bk * NCH + c) * DI + d) * 16 + ng * 4;
    *(float4*)(aprod + idx) = make_float4(p0, p1, p2, p3);
    *(float4*)(hend + idx)  = make_float4(h0, h1, h2, h3);
}

// ---------------- K4b: scan across chunks (exclusive) ----------------------
__global__ __launch_bounds__(256) void k_scan_b(const float* __restrict__ aprod,
                                                const float* __restrict__ hend,
                                                float* __restrict__ hinit) {
    int t = blockIdx.x * 256 + threadIdx.x;  // < 4*192*16 = 12288
    int bk = t / 3072;
    int r = t % 3072;
    float carry = 0.f;
    for (int c = 0; c < NCH; ++c) {
        size_t idx = ((size_t)bk * NCH + c) * 3072 + r;
        hinit[idx] = carry;
        carry = fmaf(aprod[idx], carry, hend[idx]);
    }
}

// ---------------- K4c: replay chunks with h_init, emit y -------------------
__global__ __launch_bounds__(256) void k_scan_c(const float* __restrict__ delta,
                                                const float* __restrict__ xs0,
                                                const float* __restrict__ Bsv,
                                                const float* __restrict__ Csv,
                                                const float* __restrict__ A_logs,
                                                const float* __restrict__ hinit,
                                                float* __restrict__ ya,
                                                float* __restrict__ yb) {
    int blk = blockIdx.x;
    int c = blk & (NCH - 1);
    int rest = blk >> 7;
    int dt = rest % 3;
    int bk = rest / 3;
    int b = bk >> 1, k = bk & 1;
    int tid = threadIdx.x;
    int dd = tid >> 2, ng = tid & 3;
    int d = dt * 64 + dd;

    const size_t abase = ((size_t)k * DI + d) * 16 + ng * 4;
    float Av0 = -expf(A_logs[abase + 0]);
    float Av1 = -expf(A_logs[abase + 1]);
    float Av2 = -expf(A_logs[abase + 2]);
    float Av3 = -expf(A_logs[abase + 3]);

    size_t sidx = (((size_t)bk * NCH + c) * DI + d) * 16 + ng * 4;
    float4 hv = *(const float4*)(hinit + sidx);
    float h0 = hv.x, h1 = hv.y, h2 = hv.z, h3 = hv.w;

    const int posbase = bk << 12;
#pragma unroll 4
    for (int l = 0; l < CT; ++l) {
        int gl = c * CT + l;
        float dl = delta[((size_t)(posbase + gl)) * DI + d];
        int msrc = k ? (4095 - gl) : gl;
        float xv = xs0[((size_t)(b << 12) + msrc) * DI + d];
        float4 bv = *(const float4*)(Bsv + ((size_t)(posbase + gl)) * 16 + ng * 4);
        float4 cv = *(const float4*)(Csv + ((size_t)(posbase + gl)) * 16 + ng * 4);
        float dx = dl * xv;
        float a0 = expf(dl * Av0), a1 = expf(dl * Av1);
        float a2 = expf(dl * Av2), a3 = expf(dl * Av3);
        h0 = a0 * h0 + dx * bv.x; h1 = a1 * h1 + dx * bv.y;
        h2 = a2 * h2 + dx * bv.z; h3 = a3 * h3 + dx * bv.w;
        float p = h0 * cv.x + h1 * cv.y + h2 * cv.z + h3 * cv.w;
        p += __shfl_xor(p, 1);
        p += __shfl_xor(p, 2);
        if (ng == 0) {
            if (k == 0) ya[((size_t)(b << 12) + gl) * DI + d] = p;
            else        yb[((size_t)(b << 12) + (4095 - gl)) * DI + d] = p;
        }
    }
}

// ---------------- K5a: combine dirs + D*x, un-permute, LN, *silu(z) --------
// one row (spatial position) per 192-thread block; pure streaming
__global__ __launch_bounds__(192) void k_ln(const float* __restrict__ ya,
                                            const float* __restrict__ yb,
                                            const float* __restrict__ xs0,
                                            const float* __restrict__ Ds,
                                            const float* __restrict__ zs,
                                            const float* __restrict__ ln_g,
                                            const float* __restrict__ ln_b,
                                            float* __restrict__ ymod) {
    __shared__ float red[6];

    int p = blockIdx.x & 4095;
    int b = blockIdx.x >> 12;
    int i = p >> 6, j = p & 63;
    int m = inv_ord(i, j);
    int d = threadIdx.x;  // 0..191

    size_t base = ((size_t)(b << 12) + m) * DI + d;
    float v = ya[base] + yb[base] + (Ds[d] + Ds[DI + d]) * xs0[base];

    float s = v, s2 = v * v;
#pragma unroll
    for (int off = 32; off; off >>= 1) {
        s += __shfl_xor(s, off);
        s2 += __shfl_xor(s2, off);
    }
    int wv = d >> 6, ln = d & 63;
    if (ln == 0) { red[wv] = s; red[3 + wv] = s2; }
    __syncthreads();
    float sum = red[0] + red[1] + red[2];
    float sum2 = red[3] + red[4] + red[5];
    float mu = sum * (1.f / 192.f);
    float var = sum2 * (1.f / 192.f) - mu * mu;
    float isd = rsqrtf(var + 1e-5f);
    float yn = (v - mu) * isd * ln_g[d] + ln_b[d];
    float ym = yn * zs[((size_t)(b << 12) + p) * DI + d];
    ymod[((size_t)(b << 12) + p) * DI + d] = ym;
}

// ---------------- K5b: out = ymod @ w_out^T  (M=8192, N=96, K=192) ---------
// tile 32(M) x 96(N, full), K in 2 tiles of 96; 256 threads, acc 2x6
__global__ __launch_bounds__(256) void k_gemm_out(const float* __restrict__ ymod,
                                                  const float* __restrict__ w_out,
                                                  float* __restrict__ out) {
    __shared__ float aT[96][36];    // [k][m] for 32 rows, padded
    __shared__ float bT[96][104];   // [k][n] for 96 cols, padded
    const int tid = threadIdx.x;
    const int bm = blockIdx.x;      // 256 tiles of 32 rows
    const int tn = tid & 15, tm = tid >> 4;   // tn 0..15 (6 cols each), tm 0..15 (2 rows each)

    float acc[2][6] = {};
#pragma unroll
    for (int kt = 0; kt < 2; ++kt) {
        __syncthreads();
        for (int f = tid; f < 32 * 24; f += 256) {
            int mm = f / 24, k4 = f % 24;
            float4 v = *(const float4*)(ymod + (size_t)(bm * 32 + mm) * DI + kt * 96 + k4 * 4);
            aT[k4 * 4 + 0][mm] = v.x; aT[k4 * 4 + 1][mm] = v.y;
            aT[k4 * 4 + 2][mm] = v.z; aT[k4 * 4 + 3][mm] = v.w;
        }
        for (int f = tid; f < 96 * 24; f += 256) {
            int nn = f / 24, k4 = f % 24;
            float4 v = *(const float4*)(w_out + (size_t)nn * DI + kt * 96 + k4 * 4);
            bT[k4 * 4 + 0][nn] = v.x; bT[k4 * 4 + 1][nn] = v.y;
            bT[k4 * 4 + 2][nn] = v.z; bT[k4 * 4 + 3][nn] = v.w;
        }
        __syncthreads();
#pragma unroll 4
        for (int k = 0; k < 96; ++k) {
            float2 av = *(const float2*)&aT[k][tm * 2];
            float2 b0 = *(const float2*)&bT[k][tn * 6];
            float2 b1 = *(const float2*)&bT[k][tn * 6 + 2];
            float2 b2 = *(const float2*)&bT[k][tn * 6 + 4];
            acc[0][0] += av.x * b0.x; acc[0][1] += av.x * b0.y;
            acc[0][2] += av.x * b1.x; acc[0][3] += av.x * b1.y;
            acc[0][4] += av.x * b2.x; acc[0][5] += av.x * b2.y;
            acc[1][0] += av.y * b0.x; acc[1][1] += av.y * b0.y;
            acc[1][2] += av.y * b1.x; acc[1][3] += av.y * b1.y;
            acc[1][4] += av.y * b2.x; acc[1][5] += av.y * b2.y;
        }
    }

#pragma unroll
    for (int i = 0; i < 2; ++i) {
        int m = bm * 32 + tm * 2 + i;
#pragma unroll
        for (int j = 0; j < 6; ++j) {
            out[(size_t)m * DM + tn * 6 + j] = acc[i][j];
        }
    }
}

extern "C" void kernel_launch(void* const* d_in, const int* in_sizes, int n_in,
                              void* d_out, int out_size, void* d_ws, size_t ws_size,
                              hipStream_t stream) {
    (void)in_sizes; (void)n_in; (void)out_size; (void)ws_size;
    const float* x      = (const float*)d_in[0];
    const float* w_in   = (const float*)d_in[1];
    const float* conv_w = (const float*)d_in[2];
    const float* conv_b = (const float*)d_in[3];
    const float* xpw    = (const float*)d_in[4];
    const float* dtw    = (const float*)d_in[5];
    const float* dtb    = (const float*)d_in[6];
    const float* A_logs = (const float*)d_in[7];
    const float* Ds     = (const float*)d_in[8];
    const float* ln_g   = (const float*)d_in[9];
    const float* ln_b   = (const float*)d_in[10];
    const float* w_out  = (const float*)d_in[11];
    float* out = (float*)d_out;

    // workspace layout (floats); total ~18.35M floats = ~73.4 MB
    float* ws    = (float*)d_ws;
    float* xi    = ws;                       // B*L*DI       = 1,572,864
    float* zs    = xi + 1572864;             // 1,572,864
    float* xs0   = zs + 1572864;             // 1,572,864
    float* delta = xs0 + 1572864;            // B*K*L*DI     = 6,291,456
    float* Bsv   = delta + 6291456;          // B*K*L*16     =   524,288
    float* Csv   = Bsv + 524288;             //                  524,288
    float* aprod = Csv + 524288;             // 4*NCH*DI*16  = 1,572,864
    float* hend  = aprod + 1572864;          // 1,572,864
    float* hinit = hend + 1572864;           // 1,572,864
    float* ya    = hinit + 1572864;          // 1,572,864
    float* yb    = ya + 1572864;             // 1,572,864
    float* ymod  = delta;                    // delta is dead after k_scan_c; reuse

    k_gemm_in<<<dim3(128, 6), 256, 0, stream>>>(x, w_in, xi, zs);
    k_conv<<<1536, 256, 0, stream>>>(xi, conv_w, conv_b, xs0);
    k_proj2<<<256, 256, 0, stream>>>(xs0, xpw, dtw, dtb, delta, Bsv, Csv);
    k_scan_a<<<4 * 3 * NCH, 256, 0, stream>>>(delta, xs0, Bsv, A_logs, aprod, hend);
    k_scan_b<<<48, 256, 0, stream>>>(aprod, hend, hinit);
    k_scan_c<<<4 * 3 * NCH, 256, 0, stream>>>(delta, xs0, Bsv, Csv, A_logs, hinit, ya, yb);
    k_ln<<<8192, 192, 0, stream>>>(ya, yb, xs0, Ds, zs, ln_g, ln_b, ymod);
    k_gemm_out<<<256, 256, 0, stream>>>(ymod, w_out, out);
}

// Round 4
// 180.736 us; speedup vs baseline: 1.0919x; 1.0919x over previous
//
#include <hip/hip_runtime.h>
#include <math.h>

// Problem constants
#define BB 2
#define DM 96
#define DI 192
#define DST 16
#define DRK 6
#define LL 4096
#define NCH 128     // number of scan chunks
#define CT 32       // chunk length (NCH*CT == LL)

// spatial (i,j) -> scan index, closed form of diagonal_order's argsort
__device__ __forceinline__ int inv_ord(int i, int j) {
    if (i == j) return i;
    if (j > i)  return 64 + i * 63 - (i * (i - 1)) / 2 + (j - i - 1);
    return 2080 + (i * (i - 1)) / 2 + j;
}

__device__ __forceinline__ float silu_f(float v) {
    return v / (1.f + expf(-v));
}

// ---------------- K1: xz = x @ w_in^T ; split into xi and silu(z) ----------
// M = B*H*W = 8192, N = 384, K = 96. Tile 64x64, block 256, whole K in LDS.
__global__ __launch_bounds__(256) void k_gemm_in(const float* __restrict__ x,
                                                 const float* __restrict__ w_in,
                                                 float* __restrict__ xi,
                                                 float* __restrict__ zs) {
    __shared__ float aT[96][68];   // [k][m], padded for b128-aligned reads
    __shared__ float bT[96][68];   // [k][n]
    const int tid = threadIdx.x;
    const int bm = blockIdx.x, bn = blockIdx.y;

    for (int f = tid; f < 64 * 24; f += 256) {
        int mm = f / 24, k4 = f % 24;
        float4 v = *(const float4*)(x + (size_t)(bm * 64 + mm) * 96 + k4 * 4);
        aT[k4 * 4 + 0][mm] = v.x; aT[k4 * 4 + 1][mm] = v.y;
        aT[k4 * 4 + 2][mm] = v.z; aT[k4 * 4 + 3][mm] = v.w;
    }
    for (int f = tid; f < 64 * 24; f += 256) {
        int nn = f / 24, k4 = f % 24;
        float4 v = *(const float4*)(w_in + (size_t)(bn * 64 + nn) * 96 + k4 * 4);
        bT[k4 * 4 + 0][nn] = v.x; bT[k4 * 4 + 1][nn] = v.y;
        bT[k4 * 4 + 2][nn] = v.z; bT[k4 * 4 + 3][nn] = v.w;
    }
    __syncthreads();

    const int tn = tid & 15, tm = tid >> 4;
    float acc[4][4] = {};
#pragma unroll 4
    for (int k = 0; k < 96; ++k) {
        float4 av = *(const float4*)&aT[k][tm * 4];
        float4 bv = *(const float4*)&bT[k][tn * 4];
        acc[0][0] += av.x * bv.x; acc[0][1] += av.x * bv.y; acc[0][2] += av.x * bv.z; acc[0][3] += av.x * bv.w;
        acc[1][0] += av.y * bv.x; acc[1][1] += av.y * bv.y; acc[1][2] += av.y * bv.z; acc[1][3] += av.y * bv.w;
        acc[2][0] += av.z * bv.x; acc[2][1] += av.z * bv.y; acc[2][2] += av.z * bv.z; acc[2][3] += av.z * bv.w;
        acc[3][0] += av.w * bv.x; acc[3][1] += av.w * bv.y; acc[3][2] += av.w * bv.z; acc[3][3] += av.w * bv.w;
    }

#pragma unroll
    for (int i = 0; i < 4; ++i) {
#pragma unroll
        for (int j = 0; j < 4; ++j) {
            int m = bm * 64 + tm * 4 + i;
            int n = bn * 64 + tn * 4 + j;
            float v = acc[i][j];
            if (n < DI) xi[(size_t)m * DI + n] = v;
            else        zs[(size_t)m * DI + (n - DI)] = silu_f(v);
        }
    }
}

// ---------------- K2: depthwise 3x3 conv + bias + silu, write in scan order
__global__ __launch_bounds__(256) void k_conv(const float* __restrict__ xi,
                                              const float* __restrict__ cw,
                                              const float* __restrict__ cb,
                                              float* __restrict__ xs0) {
    int t = blockIdx.x * 256 + threadIdx.x;   // < 2*4096*48
    int c4 = t % 48;
    int p = t / 48;
    int b = p >> 12;
    int hw = p & 4095;
    int i = hw >> 6, j = hw & 63;
    int c = c4 * 4;
    float a0 = cb[c], a1 = cb[c + 1], a2 = cb[c + 2], a3 = cb[c + 3];
#pragma unroll
    for (int kh = -1; kh <= 1; ++kh) {
        int i2 = i + kh;
        if (i2 < 0 || i2 > 63) continue;
#pragma unroll
        for (int kw = -1; kw <= 1; ++kw) {
            int j2 = j + kw;
            if (j2 < 0 || j2 > 63) continue;
            float4 v = *(const float4*)(xi + ((size_t)(b << 12) + (i2 << 6) + j2) * DI + c);
            int wi = (kh + 1) * 3 + (kw + 1);
            a0 += v.x * cw[(c + 0) * 9 + wi];
            a1 += v.y * cw[(c + 1) * 9 + wi];
            a2 += v.z * cw[(c + 2) * 9 + wi];
            a3 += v.w * cw[(c + 3) * 9 + wi];
        }
    }
    a0 = silu_f(a0); a1 = silu_f(a1); a2 = silu_f(a2); a3 = silu_f(a3);
    int m = inv_ord(i, j);
    *(float4*)(xs0 + ((size_t)(b << 12) + m) * DI + c) = make_float4(a0, a1, a2, a3);
}

// ---------------- K3: x-proj (38x192) + dt-proj (192x6) + softplus ---------
// 32 positions/block, 512 blocks (2/CU), ~30KB LDS. lane=pos in phase 1,
// no shuffles; short independent loops.
__global__ __launch_bounds__(256) void k_proj3(const float* __restrict__ xs0,
                                               const float* __restrict__ xpw,
                                               const float* __restrict__ dtw,
                                               const float* __restrict__ dtb,
                                               float* __restrict__ delta,
                                               float* __restrict__ Bsv,
                                               float* __restrict__ Csv) {
    __shared__ float4 xls[48][33];   // [q][pos], padded: 25.3 KB
    __shared__ float  tls[38][33];   // [c][pos]: 5.0 KB
    const int tid = threadIdx.x;
    const int bk = blockIdx.x >> 7;   // 0..3  (b,k)
    const int pc = blockIdx.x & 127;  // 32-position chunk within bk
    const int b = bk >> 1, k = bk & 1;

    // stage 32 x-rows (scan order for this k) into LDS, coalesced reads
    for (int f = tid; f < 32 * 48; f += 256) {
        int row = f / 48, q = f % 48;
        int l = pc * 32 + row;
        int msrc = k ? (4095 - l) : l;
        xls[q][row] = *(const float4*)(xs0 + ((size_t)(b << 12) + msrc) * DI + q * 4);
    }
    __syncthreads();

    // phase 1: t[c][pos] = dot(xpw[k][c][:], x[pos][:])
    // lane = pos (tid&31); 8 channel-groups (tid>>5) of 5/4 channels
    {
        int pos = tid & 31, cg = tid >> 5;
        int cbase = (cg < 6) ? cg * 5 : 30 + (cg - 6) * 4;
        int nch = (cg < 6) ? 5 : 4;
        const float* wb = xpw + (size_t)k * 38 * DI;
        const float4* w0 = (const float4*)(wb + (size_t)(cbase + 0) * DI);
        const float4* w1 = (const float4*)(wb + (size_t)(cbase + 1) * DI);
        const float4* w2 = (const float4*)(wb + (size_t)(cbase + 2) * DI);
        const float4* w3 = (const float4*)(wb + (size_t)(cbase + 3) * DI);
        const float4* w4 = (const float4*)(wb + (size_t)(cbase + (nch > 4 ? 4 : 3)) * DI);
        float a0 = 0.f, a1 = 0.f, a2 = 0.f, a3 = 0.f, a4 = 0.f;
#pragma unroll 4
        for (int q = 0; q < 48; ++q) {
            float4 xv = xls[q][pos];
            float4 v0 = w0[q], v1 = w1[q], v2 = w2[q], v3 = w3[q], v4 = w4[q];
            a0 += xv.x * v0.x + xv.y * v0.y + xv.z * v0.z + xv.w * v0.w;
            a1 += xv.x * v1.x + xv.y * v1.y + xv.z * v1.z + xv.w * v1.w;
            a2 += xv.x * v2.x + xv.y * v2.y + xv.z * v2.z + xv.w * v2.w;
            a3 += xv.x * v3.x + xv.y * v3.y + xv.z * v3.z + xv.w * v3.w;
            a4 += xv.x * v4.x + xv.y * v4.y + xv.z * v4.z + xv.w * v4.w;
        }
        tls[cbase + 0][pos] = a0;
        tls[cbase + 1][pos] = a1;
        tls[cbase + 2][pos] = a2;
        tls[cbase + 3][pos] = a3;
        if (nch > 4) tls[cbase + 4][pos] = a4;
    }
    __syncthreads();

    // phase 2a (threads 0-191): dt-proj + softplus, d = tid, coalesced stores
    if (tid < DI) {
        int d = tid;
        const float* dwr = dtw + ((size_t)k * DI + d) * 6;
        float w0 = dwr[0], w1 = dwr[1], w2 = dwr[2];
        float w3 = dwr[3], w4 = dwr[4], w5 = dwr[5];
        float bias = dtb[k * DI + d];
        int posg0 = (bk << 12) + pc * 32;
#pragma unroll 4
        for (int pos = 0; pos < 32; ++pos) {
            float acc = bias
                + tls[0][pos] * w0 + tls[1][pos] * w1
                + tls[2][pos] * w2 + tls[3][pos] * w3
                + tls[4][pos] * w4 + tls[5][pos] * w5;
            float sp = acc > 20.f ? acc : log1pf(expf(acc));
            delta[(size_t)(posg0 + pos) * DI + d] = sp;
        }
    } else {
        // phase 2b (threads 192-255): emit B (tid&32==0) or C
        int t2 = tid - DI;
        int pos = t2 & 31, bc = t2 >> 5;
        size_t posg = (size_t)(bk << 12) + pc * 32 + pos;
        int cb2 = bc ? 22 : 6;
        float* dst = bc ? Csv : Bsv;
#pragma unroll
        for (int q2 = 0; q2 < 4; ++q2) {
            float4 v = make_float4(tls[cb2 + q2 * 4 + 0][pos],
                                   tls[cb2 + q2 * 4 + 1][pos],
                                   tls[cb2 + q2 * 4 + 2][pos],
                                   tls[cb2 + q2 * 4 + 3][pos]);
            *(float4*)(dst + posg * 16 + q2 * 4) = v;
        }
    }
}

// ---------------- K4a: per-chunk scan from h=0, record (prod a, h_end) -----
__global__ __launch_bounds__(256) void k_scan_a(const float* __restrict__ delta,
                                                const float* __restrict__ xs0,
                                                const float* __restrict__ Bsv,
                                                const float* __restrict__ A_logs,
                                                float* __restrict__ aprod,
                                                float* __restrict__ hend) {
    int blk = blockIdx.x;                // 4*3*NCH
    int c = blk & (NCH - 1);
    int rest = blk >> 7;
    int dt = rest % 3;
    int bk = rest / 3;
    int b = bk >> 1, k = bk & 1;
    int tid = threadIdx.x;
    int dd = tid >> 2, ng = tid & 3;
    int d = dt * 64 + dd;

    const size_t abase = ((size_t)k * DI + d) * 16 + ng * 4;
    float Av0 = -expf(A_logs[abase + 0]);
    float Av1 = -expf(A_logs[abase + 1]);
    float Av2 = -expf(A_logs[abase + 2]);
    float Av3 = -expf(A_logs[abase + 3]);

    float h0 = 0, h1 = 0, h2 = 0, h3 = 0;
    float p0 = 1, p1 = 1, p2 = 1, p3 = 1;
    const int posbase = bk << 12;
#pragma unroll 4
    for (int l = 0; l < CT; ++l) {
        int gl = c * CT + l;
        float dl = delta[((size_t)(posbase + gl)) * DI + d];
        int msrc = k ? (4095 - gl) : gl;
        float xv = xs0[((size_t)(b << 12) + msrc) * DI + d];
        float4 bv = *(const float4*)(Bsv + ((size_t)(posbase + gl)) * 16 + ng * 4);
        float dx = dl * xv;
        float a0 = expf(dl * Av0), a1 = expf(dl * Av1);
        float a2 = expf(dl * Av2), a3 = expf(dl * Av3);
        h0 = a0 * h0 + dx * bv.x; h1 = a1 * h1 + dx * bv.y;
        h2 = a2 * h2 + dx * bv.z; h3 = a3 * h3 + dx * bv.w;
        p0 *= a0; p1 *= a1; p2 *= a2; p3 *= a3;
    }
    size_t idx = (((size_t)bk * NCH + c) * DI + d) * 16 + ng * 4;
    *(float4*)(aprod + idx) = make_float4(p0, p1, p2, p3);
    *(float4*)(hend + idx)  = make_float4(h0, h1, h2, h3);
}

// ---------------- K4b: scan across chunks (exclusive) ----------------------
__global__ __launch_bounds__(256) void k_scan_b(const float* __restrict__ aprod,
                                                const float* __restrict__ hend,
                                                float* __restrict__ hinit) {
    int t = blockIdx.x * 256 + threadIdx.x;  // < 4*192*16 = 12288
    int bk = t / 3072;
    int r = t % 3072;
    float carry = 0.f;
    for (int c = 0; c < NCH; ++c) {
        size_t idx = ((size_t)bk * NCH + c) * 3072 + r;
        hinit[idx] = carry;
        carry = fmaf(aprod[idx], carry, hend[idx]);
    }
}

// ---------------- K4c: replay chunks with h_init, emit y -------------------
__global__ __launch_bounds__(256) void k_scan_c(const float* __restrict__ delta,
                                                const float* __restrict__ xs0,
                                                const float* __restrict__ Bsv,
                                                const float* __restrict__ Csv,
                                                const float* __restrict__ A_logs,
                                                const float* __restrict__ hinit,
                                                float* __restrict__ ya,
                                                float* __restrict__ yb) {
    int blk = blockIdx.x;
    int c = blk & (NCH - 1);
    int rest = blk >> 7;
    int dt = rest % 3;
    int bk = rest / 3;
    int b = bk >> 1, k = bk & 1;
    int tid = threadIdx.x;
    int dd = tid >> 2, ng = tid & 3;
    int d = dt * 64 + dd;

    const size_t abase = ((size_t)k * DI + d) * 16 + ng * 4;
    float Av0 = -expf(A_logs[abase + 0]);
    float Av1 = -expf(A_logs[abase + 1]);
    float Av2 = -expf(A_logs[abase + 2]);
    float Av3 = -expf(A_logs[abase + 3]);

    size_t sidx = (((size_t)bk * NCH + c) * DI + d) * 16 + ng * 4;
    float4 hv = *(const float4*)(hinit + sidx);
    float h0 = hv.x, h1 = hv.y, h2 = hv.z, h3 = hv.w;

    const int posbase = bk << 12;
#pragma unroll 4
    for (int l = 0; l < CT; ++l) {
        int gl = c * CT + l;
        float dl = delta[((size_t)(posbase + gl)) * DI + d];
        int msrc = k ? (4095 - gl) : gl;
        float xv = xs0[((size_t)(b << 12) + msrc) * DI + d];
        float4 bv = *(const float4*)(Bsv + ((size_t)(posbase + gl)) * 16 + ng * 4);
        float4 cv = *(const float4*)(Csv + ((size_t)(posbase + gl)) * 16 + ng * 4);
        float dx = dl * xv;
        float a0 = expf(dl * Av0), a1 = expf(dl * Av1);
        float a2 = expf(dl * Av2), a3 = expf(dl * Av3);
        h0 = a0 * h0 + dx * bv.x; h1 = a1 * h1 + dx * bv.y;
        h2 = a2 * h2 + dx * bv.z; h3 = a3 * h3 + dx * bv.w;
        float p = h0 * cv.x + h1 * cv.y + h2 * cv.z + h3 * cv.w;
        p += __shfl_xor(p, 1);
        p += __shfl_xor(p, 2);
        if (ng == 0) {
            if (k == 0) ya[((size_t)(b << 12) + gl) * DI + d] = p;
            else        yb[((size_t)(b << 12) + (4095 - gl)) * DI + d] = p;
        }
    }
}

// ---------------- K5a: combine dirs + D*x, un-permute, LN, *silu(z) --------
// one row (spatial position) per 192-thread block; pure streaming
__global__ __launch_bounds__(192) void k_ln(const float* __restrict__ ya,
                                            const float* __restrict__ yb,
                                            const float* __restrict__ xs0,
                                            const float* __restrict__ Ds,
                                            const float* __restrict__ zs,
                                            const float* __restrict__ ln_g,
                                            const float* __restrict__ ln_b,
                                            float* __restrict__ ymod) {
    __shared__ float red[6];

    int p = blockIdx.x & 4095;
    int b = blockIdx.x >> 12;
    int i = p >> 6, j = p & 63;
    int m = inv_ord(i, j);
    int d = threadIdx.x;  // 0..191

    size_t base = ((size_t)(b << 12) + m) * DI + d;
    float v = ya[base] + yb[base] + (Ds[d] + Ds[DI + d]) * xs0[base];

    float s = v, s2 = v * v;
#pragma unroll
    for (int off = 32; off; off >>= 1) {
        s += __shfl_xor(s, off);
        s2 += __shfl_xor(s2, off);
    }
    int wv = d >> 6, ln = d & 63;
    if (ln == 0) { red[wv] = s; red[3 + wv] = s2; }
    __syncthreads();
    float sum = red[0] + red[1] + red[2];
    float sum2 = red[3] + red[4] + red[5];
    float mu = sum * (1.f / 192.f);
    float var = sum2 * (1.f / 192.f) - mu * mu;
    float isd = rsqrtf(var + 1e-5f);
    float yn = (v - mu) * isd * ln_g[d] + ln_b[d];
    float ym = yn * zs[((size_t)(b << 12) + p) * DI + d];
    ymod[((size_t)(b << 12) + p) * DI + d] = ym;
}

// ---------------- K5b: out = ymod @ w_out^T  (M=8192, N=96, K=192) ---------
// tile 32(M) x 96(N, full), K in 2 tiles of 96; 256 threads, acc 2x6
__global__ __launch_bounds__(256) void k_gemm_out(const float* __restrict__ ymod,
                                                  const float* __restrict__ w_out,
                                                  float* __restrict__ out) {
    __shared__ float aT[96][36];    // [k][m] for 32 rows, padded
    __shared__ float bT[96][104];   // [k][n] for 96 cols, padded
    const int tid = threadIdx.x;
    const int bm = blockIdx.x;      // 256 tiles of 32 rows
    const int tn = tid & 15, tm = tid >> 4;   // tn 0..15 (6 cols each), tm 0..15 (2 rows each)

    float acc[2][6] = {};
#pragma unroll
    for (int kt = 0; kt < 2; ++kt) {
        __syncthreads();
        for (int f = tid; f < 32 * 24; f += 256) {
            int mm = f / 24, k4 = f % 24;
            float4 v = *(const float4*)(ymod + (size_t)(bm * 32 + mm) * DI + kt * 96 + k4 * 4);
            aT[k4 * 4 + 0][mm] = v.x; aT[k4 * 4 + 1][mm] = v.y;
            aT[k4 * 4 + 2][mm] = v.z; aT[k4 * 4 + 3][mm] = v.w;
        }
        for (int f = tid; f < 96 * 24; f += 256) {
            int nn = f / 24, k4 = f % 24;
            float4 v = *(const float4*)(w_out + (size_t)nn * DI + kt * 96 + k4 * 4);
            bT[k4 * 4 + 0][nn] = v.x; bT[k4 * 4 + 1][nn] = v.y;
            bT[k4 * 4 + 2][nn] = v.z; bT[k4 * 4 + 3][nn] = v.w;
        }
        __syncthreads();
#pragma unroll 4
        for (int k = 0; k < 96; ++k) {
            float2 av = *(const float2*)&aT[k][tm * 2];
            float2 b0 = *(const float2*)&bT[k][tn * 6];
            float2 b1 = *(const float2*)&bT[k][tn * 6 + 2];
            float2 b2 = *(const float2*)&bT[k][tn * 6 + 4];
            acc[0][0] += av.x * b0.x; acc[0][1] += av.x * b0.y;
            acc[0][2] += av.x * b1.x; acc[0][3] += av.x * b1.y;
            acc[0][4] += av.x * b2.x; acc[0][5] += av.x * b2.y;
            acc[1][0] += av.y * b0.x; acc[1][1] += av.y * b0.y;
            acc[1][2] += av.y * b1.x; acc[1][3] += av.y * b1.y;
            acc[1][4] += av.y * b2.x; acc[1][5] += av.y * b2.y;
        }
    }

#pragma unroll
    for (int i = 0; i < 2; ++i) {
        int m = bm * 32 + tm * 2 + i;
#pragma unroll
        for (int j = 0; j < 6; ++j) {
            out[(size_t)m * DM + tn * 6 + j] = acc[i][j];
        }
    }
}

extern "C" void kernel_launch(void* const* d_in, const int* in_sizes, int n_in,
                              void* d_out, int out_size, void* d_ws, size_t ws_size,
                              hipStream_t stream) {
    (void)in_sizes; (void)n_in; (void)out_size; (void)ws_size;
    const float* x      = (const float*)d_in[0];
    const float* w_in   = (const float*)d_in[1];
    const float* conv_w = (const float*)d_in[2];
    const float* conv_b = (const float*)d_in[3];
    const float* xpw    = (const float*)d_in[4];
    const float* dtw    = (const float*)d_in[5];
    const float* dtb    = (const float*)d_in[6];
    const float* A_logs = (const float*)d_in[7];
    const float* Ds     = (const float*)d_in[8];
    const float* ln_g   = (const float*)d_in[9];
    const float* ln_b   = (const float*)d_in[10];
    const float* w_out  = (const float*)d_in[11];
    float* out = (float*)d_out;

    // workspace layout (floats); total ~18.35M floats = ~73.4 MB
    float* ws    = (float*)d_ws;
    float* xi    = ws;                       // B*L*DI       = 1,572,864
    float* zs    = xi + 1572864;             // 1,572,864
    float* xs0   = zs + 1572864;             // 1,572,864
    float* delta = xs0 + 1572864;            // B*K*L*DI     = 6,291,456
    float* Bsv   = delta + 6291456;          // B*K*L*16     =   524,288
    float* Csv   = Bsv + 524288;             //                  524,288
    float* aprod = Csv + 524288;             // 4*NCH*DI*16  = 1,572,864
    float* hend  = aprod + 1572864;          // 1,572,864
    float* hinit = hend + 1572864;           // 1,572,864
    float* ya    = hinit + 1572864;          // 1,572,864
    float* yb    = ya + 1572864;             // 1,572,864
    float* ymod  = delta;                    // delta is dead after k_scan_c; reuse

    k_gemm_in<<<dim3(128, 6), 256, 0, stream>>>(x, w_in, xi, zs);
    k_conv<<<1536, 256, 0, stream>>>(xi, conv_w, conv_b, xs0);
    k_proj3<<<512, 256, 0, stream>>>(xs0, xpw, dtw, dtb, delta, Bsv, Csv);
    k_scan_a<<<4 * 3 * NCH, 256, 0, stream>>>(delta, xs0, Bsv, A_logs, aprod, hend);
    k_scan_b<<<48, 256, 0, stream>>>(aprod, hend, hinit);
    k_scan_c<<<4 * 3 * NCH, 256, 0, stream>>>(delta, xs0, Bsv, Csv, A_logs, hinit, ya, yb);
    k_ln<<<8192, 192, 0, stream>>>(ya, yb, xs0, Ds, zs, ln_g, ln_b, ymod);
    k_gemm_out<<<256, 256, 0, stream>>>(ymod, w_out, out);
}